// Round 9
// baseline (101.488 us; speedup 1.0000x reference)
//
#include <hip/hip_runtime.h>
#include <hip/hip_bf16.h>

#define DIM 1024
#define STATE 256
#define BATCH 4
#define SEQ 4096
#define M_TOT (BATCH * SEQ)  // 16384

typedef short short8 __attribute__((ext_vector_type(8)));
typedef float f32x4 __attribute__((ext_vector_type(4)));

__device__ __forceinline__ unsigned short f2bf(float f) {
  unsigned int u = __float_as_uint(f);
  u += 0x7fff + ((u >> 16) & 1);  // RNE
  return (unsigned short)(u >> 16);
}

__device__ __forceinline__ void gl_lds16(const void* g, void* l) {
  __builtin_amdgcn_global_load_lds(
      (const __attribute__((address_space(1))) void*)g,
      (__attribute__((address_space(3))) void*)l, 16, 0, 0);
}

#define C2F 2.8853900817779268f   // 2*log2(e)
#define LOG2EF 1.4426950408889634f
#define VMC(N) asm volatile("s_waitcnt vmcnt(" #N ")" ::: "memory")

// ---------------- convert_w: weights + constants only ------------------------
__global__ __launch_bounds__(256) void convert_w(
    const float* __restrict__ A, const float* __restrict__ Bw,
    const float* __restrict__ Bb, const float* __restrict__ Cw,
    const float* __restrict__ Cb, const float* __restrict__ Dw,
    const float* __restrict__ Db, unsigned short* __restrict__ bwb,
    unsigned short* __restrict__ wob, float* __restrict__ bb2,
    float* __restrict__ mP2, float* __restrict__ cbdb) {
  const int bx = blockIdx.x;
  const int t = threadIdx.x;
  if (bx < 256) {                      // bwb row per block
    int c = t * 4;
    const float4 v = *(const float4*)(Bw + (size_t)bx * DIM + c);
    *(ushort4*)(bwb + (size_t)bx * DIM + c) =
        make_ushort4(f2bf(v.x), f2bf(v.y), f2bf(v.z), f2bf(v.w));
  } else if (bx < 256 + 1024) {        // wob row e = [Cw[e,:] | Dw[e,:]]
    int e = bx - 256;
    if (t < 64) {
      const float4 v = *(const float4*)(Cw + (size_t)e * STATE + t * 4);
      *(ushort4*)(wob + (size_t)e * 1280 + t * 4) =
          make_ushort4(f2bf(v.x), f2bf(v.y), f2bf(v.z), f2bf(v.w));
    }
    const float4 v = *(const float4*)(Dw + (size_t)e * DIM + t * 4);
    *(ushort4*)(wob + (size_t)e * 1280 + 256 + t * 4) =
        make_ushort4(f2bf(v.x), f2bf(v.y), f2bf(v.z), f2bf(v.w));
  } else {                             // scan constants + out bias, one block
    const float P = C2F * __builtin_amdgcn_exp2f(A[t] * LOG2EF);
    bb2[t] = fmaf(Bb[t], C2F, P);
    mP2[t] = -2.0f * P;
#pragma unroll
    for (int k = 0; k < 4; ++k) {
      const int i = t * 4 + k;
      cbdb[i] = Cb[i] + Db[i];
    }
  }
}

// ---------------- gemm_GX v3 (unchanged from r8) -----------------------------
__global__ __launch_bounds__(256, 2) void gemm_GX(
    const float* __restrict__ x,             // [16384][1024] f32
    const unsigned short* __restrict__ bwb,  // [256][1024] bf16
    float* __restrict__ G,                   // [16384][256] f32
    const float* __restrict__ bb2,
    unsigned short* __restrict__ xb)         // [16384][1024] bf16 (out)
{
  __shared__ char lds[81920];  // 4 slots x 20480 (A f32 4KB @0, B bf16 16KB @4096)

  const int tid = threadIdx.x;
  const int wave = tid >> 6;   // n-column group 0..3
  const int lane = tid & 63;
  const int lr = lane & 15;
  const int lk = lane >> 4;
  const int m0 = blockIdx.x * 32;

  f32x4 acc[2][4];
#pragma unroll
  for (int i = 0; i < 2; ++i)
#pragma unroll
    for (int j = 0; j < 4; ++j) acc[i][j] = (f32x4){0.f, 0.f, 0.f, 0.f};

  const char* xB  = (const char*)x;
  const char* bwB = (const char*)bwb;
  char* xbB = (char*)xb;

  auto stage = [&](int kt) {
    if (kt >= 32) return;
    char* slot = lds + (kt & 3) * 20480;
    {  // A: [32 rows][128B f32], chunk XOR (r&7); source pre-swizzled
      const int r = tid >> 3;
      const int c = (tid & 7) ^ (r & 7);
      gl_lds16(xB + (size_t)(m0 + r) * 4096 + (size_t)kt * 128 + c * 16,
               slot + wave * 1024);
    }
#pragma unroll
    for (int i = 0; i < 4; ++i) {  // B: row-pair layout [p=n>>1][128B], XOR(p&7)
      const int s = i * 256 + tid;
      const int p = s >> 3;
      const int cp = s & 7;
      const int c = cp ^ (p & 7);
      const int n = 2 * p + (c >> 2);
      const int kc = c & 3;
      gl_lds16(bwB + (size_t)n * 2048 + (size_t)kt * 64 + kc * 16,
               slot + 4096 + i * 4096 + wave * 1024);
    }
  };

  stage(0); stage(1); stage(2);
  VMC(10);
  __builtin_amdgcn_s_barrier();

  for (int t = 0; t < 32; ++t) {
    stage(t + 3);

    const char* As = lds + (t & 3) * 20480;
    const char* Bs = As + 4096;

    short8 af[2], bfr[4];
#pragma unroll
    for (int f = 0; f < 2; ++f) {
      const int row = f * 16 + lr;
      const int sw = row & 7;
      const f32x4 a0 = *(const f32x4*)(As + row * 128 + (((2 * lk)     ^ sw) << 4));
      const f32x4 a1 = *(const f32x4*)(As + row * 128 + (((2 * lk + 1) ^ sw) << 4));
      short8 v;
#pragma unroll
      for (int j = 0; j < 4; ++j) {
        v[j]     = (short)f2bf(a0[j]);
        v[4 + j] = (short)f2bf(a1[j]);
      }
      af[f] = v;
    }
#pragma unroll
    for (int fj = 0; fj < 4; ++fj) {
      const int n = wave * 64 + fj * 16 + lr;
      const int p = n >> 1;
      const int cp = (((n & 1) * 4 + lk)) ^ (p & 7);
      bfr[fj] = *(const short8*)(Bs + p * 128 + (cp << 4));
    }
#pragma unroll
    for (int f = 0; f < 2; ++f)
#pragma unroll
      for (int fj = 0; fj < 4; ++fj)
        acc[f][fj] = __builtin_amdgcn_mfma_f32_16x16x32_bf16(af[f], bfr[fj], acc[f][fj], 0, 0, 0);

    if (((t ^ wave) & 3) == 0) {
#pragma unroll
      for (int f = 0; f < 2; ++f) {
        const int row = f * 16 + lr;
        *(short8*)(xbB + (size_t)(m0 + row) * 2048 + (size_t)t * 64 + lk * 16) = af[f];
      }
    }

    if (t < 31) {
      if (t < 29)       { VMC(10); }
      else if (t == 29) { VMC(5); }
      else              { VMC(0); }
      __builtin_amdgcn_s_barrier();
    }
  }

#pragma unroll
  for (int f = 0; f < 2; ++f)
#pragma unroll
    for (int fj = 0; fj < 4; ++fj)
#pragma unroll
      for (int j = 0; j < 4; ++j) {
        const int rg = m0 + f * 16 + lk * 4 + j;
        const int cg = wave * 64 + fj * 16 + lr;
        G[(size_t)rg * STATE + cg] = fmaf(acc[f][fj][j], C2F, bb2[cg]);
      }
}

// ---------------- chunked-parallel scan with warmup (unchanged) ---------------
__global__ __launch_bounds__(256) void scan_kernel(
    const float* __restrict__ G, const float* __restrict__ mP2arr,
    unsigned short* __restrict__ states) {
  const int b = blockIdx.x >> 6;
  const int chunk = blockIdx.x & 63;
  const int n = threadIdx.x;
  const int t0 = chunk * 64;
  const int start = (t0 > 128) ? (t0 - 128) : 0;
  const int nw = t0 - start;
  const int total = nw + 64;

  const float* g = G + ((size_t)b * SEQ + start) * STATE + n;
  unsigned short* q = states + ((size_t)b * SEQ + start) * STATE + n;
  const float mP2 = mP2arr[n];

  float r = 0.5f;
  constexpr int CH = 16;
  float cur[CH], nxt[CH];
#pragma unroll
  for (int j = 0; j < CH; ++j) cur[j] = g[(size_t)j * STATE];

  const int NC = total / CH;
  for (int c = 0; c < NC; ++c) {
    if (c + 1 < NC) {
      const float* pn = g + (size_t)(c + 1) * CH * STATE;
#pragma unroll
      for (int j = 0; j < CH; ++j) nxt[j] = pn[(size_t)j * STATE];
    }
    if (c * CH >= nw) {
      unsigned short* qc = q + (size_t)c * CH * STATE;
#pragma unroll
      for (int j = 0; j < CH; ++j) {
        const float t = fmaf(mP2, r, cur[j]);
        const float e = __builtin_amdgcn_exp2f(t);
        r = __builtin_amdgcn_rcpf(1.0f + e);
        const float s = fmaf(-2.0f, r, 1.0f);
        qc[(size_t)j * STATE] = f2bf(s);
      }
    } else {
#pragma unroll
      for (int j = 0; j < CH; ++j) {
        const float t = fmaf(mP2, r, cur[j]);
        const float e = __builtin_amdgcn_exp2f(t);
        r = __builtin_amdgcn_rcpf(1.0f + e);
      }
    }
    if (c + 1 < NC) {
#pragma unroll
      for (int j = 0; j < CH; ++j) cur[j] = nxt[j];
    }
  }
}

// ---------------- gemm_out v2: uniform-LDS-phase 8-phase schedule -------------
// dout = [states|x] @ [Cw|Dw]^T + (Cb+Db). BM=BN=256, BK=64, K=1280 (20 tiles,
// 2/iter). 8 waves (2Mx4N). LDS 128KB dbuf. B-fragment reads double-buffered in
// registers: bfrE (even tile, read in prior P7-P8, consumed P1-P4), bfrO (odd
// tile, read P3-P4, consumed P5-P8). Every phase: 4 af reads (+4 bfr reads in
// P3/P4/P7/P8) + 1 stage + barrier + 16 MFMA -> no 12-read LDS burst.
// VMC(4) at P2 (forces B(o)), P4 (A(o)), P6 (B(e+2)), P8 (A(e+2)).
__global__ __launch_bounds__(512, 2) void gemm_out(
    const unsigned short* __restrict__ stb,  // [16384][256] bf16
    const unsigned short* __restrict__ xb,   // [16384][1024] bf16
    const unsigned short* __restrict__ wob,  // [1024][1280] bf16
    const float* __restrict__ cbdb,          // [1024]
    float* __restrict__ dout)                // [16384][1024] f32
{
  __shared__ char lds[131072];  // A: 2x32KB @0, B: 2x32KB @65536

  const int tid = threadIdx.x;
  const int wave = tid >> 6;
  const int lane = tid & 63;
  const int lr = lane & 15;
  const int lk = lane >> 4;
  const int wm = wave >> 2;  // 0..1
  const int wn = wave & 3;   // 0..3

  const int bs = ((blockIdx.x & 7) << 5) | (blockIdx.x >> 3);  // XCD swizzle
  const int m0 = (bs >> 2) * 256;
  const int n0 = (bs & 3) * 256;

  const char* stbB = (const char*)stb;
  const char* xbB  = (const char*)xb;
  const char* wobB = (const char*)wob;

  f32x4 acc[8][4];
#pragma unroll
  for (int i = 0; i < 8; ++i)
#pragma unroll
    for (int j = 0; j < 4; ++j) acc[i][j] = (f32x4){0.f, 0.f, 0.f, 0.f};

  auto stageA = [&](int kt, int h) {
    if (kt >= 20) return;
    const char* base;
    size_t str;
    size_t colb;
    if (kt < 4) { base = stbB; str = 512;  colb = (size_t)kt * 128; }
    else        { base = xbB;  str = 2048; colb = (size_t)(kt - 4) * 128; }
    base += (size_t)m0 * str;
#pragma unroll
    for (int i2 = 0; i2 < 2; ++i2) {
      const int s = i2 * 512 + tid;
      const int r = s >> 3;
      const int cl = (s & 7) ^ (r & 7);
      gl_lds16(base + (size_t)(h * 128 + r) * str + colb + cl * 16,
               lds + ((kt & 1) * 32768) + h * 16384 + i2 * 8192 + wave * 1024);
    }
  };
  auto stageB = [&](int kt, int h) {
    if (kt >= 20) return;
#pragma unroll
    for (int i2 = 0; i2 < 2; ++i2) {
      const int s = i2 * 512 + tid;
      const int r = s >> 3;
      const int cl = (s & 7) ^ (r & 7);
      gl_lds16(wobB + (size_t)(n0 + h * 128 + r) * 2560 + (size_t)kt * 128 + cl * 16,
               lds + 65536 + ((kt & 1) * 32768) + h * 16384 + i2 * 8192 + wave * 1024);
    }
  };

  short8 bfrE[4][2], bfrO[4][2];

  auto rdA = [&](const char* As, int q, short8 af[2][2]) {
#pragma unroll
    for (int fl = 0; fl < 2; ++fl) {
      const int r = wm * 128 + q * 32 + fl * 16 + lr;
#pragma unroll
      for (int kk = 0; kk < 2; ++kk)
        af[fl][kk] = *(const short8*)(As + r * 128 + (((kk * 4 + lk) ^ (r & 7)) << 4));
    }
  };
  auto rdB2 = [&](const char* Bs, int fj0, short8 bfr[4][2]) {
#pragma unroll
    for (int d = 0; d < 2; ++d) {
      const int fj = fj0 + d;
      const int r = wn * 64 + fj * 16 + lr;
#pragma unroll
      for (int kk = 0; kk < 2; ++kk)
        bfr[fj][kk] = *(const short8*)(Bs + r * 128 + (((kk * 4 + lk) ^ (r & 7)) << 4));
    }
  };

#define MFMAQ(Q, BFR)                                                          \
  __builtin_amdgcn_s_setprio(1);                                               \
  _Pragma("unroll") for (int kk = 0; kk < 2; ++kk)                             \
    _Pragma("unroll") for (int fl = 0; fl < 2; ++fl)                           \
      _Pragma("unroll") for (int fj = 0; fj < 4; ++fj)                         \
        acc[(Q) * 2 + fl][fj] = __builtin_amdgcn_mfma_f32_16x16x32_bf16(       \
            af[fl][kk], BFR[fj][kk], acc[(Q) * 2 + fl][fj], 0, 0, 0);          \
  __builtin_amdgcn_s_setprio(0)

#define BAR() __builtin_amdgcn_s_barrier()

  // ---- prologue: A(0), B(0), B(1); then preload bfrE(0) ----
  stageA(0, 0); stageA(0, 1);
  stageB(0, 0); stageB(0, 1);
  stageB(1, 0); stageB(1, 1);
  VMC(4);  // A(0),B(0) complete; B(1) may fly
  BAR();
  rdB2(lds + 65536, 0, bfrE);
  rdB2(lds + 65536, 2, bfrE);

  for (int i = 0; i < 10; ++i) {
    const int e = 2 * i, o = e + 1;
    const char* Ase = lds + (e & 1) * 32768;
    const char* Aso = lds + (o & 1) * 32768;
    const char* Bso = lds + 65536 + (o & 1) * 32768;   // B(o)
    const char* Bse2 = lds + 65536 + (e & 1) * 32768;  // B(e+2) (same slot as B(e))
    short8 af[2][2];

    // P1
    rdA(Ase, 0, af); stageA(o, 0);
    BAR(); MFMAQ(0, bfrE); BAR();
    // P2
    rdA(Ase, 1, af); stageA(o, 1);
    BAR(); MFMAQ(1, bfrE); VMC(4); BAR();   // forces B(o)
    // P3
    rdA(Ase, 2, af); rdB2(Bso, 0, bfrO); stageB(e + 2, 0);
    BAR(); MFMAQ(2, bfrE); BAR();
    // P4
    rdA(Ase, 3, af); rdB2(Bso, 2, bfrO); stageB(e + 2, 1);
    BAR(); MFMAQ(3, bfrE); VMC(4); BAR();   // forces A(o)
    // P5
    rdA(Aso, 0, af); stageA(e + 2, 0);
    BAR(); MFMAQ(0, bfrO); BAR();
    // P6
    rdA(Aso, 1, af); stageA(e + 2, 1);
    BAR(); MFMAQ(1, bfrO); VMC(4); BAR();   // forces B(e+2)
    // P7
    rdA(Aso, 2, af);
    if (i < 9) rdB2(Bse2, 0, bfrE);
    stageB(o + 2, 0);
    BAR(); MFMAQ(2, bfrO); BAR();
    // P8
    rdA(Aso, 3, af);
    if (i < 9) rdB2(Bse2, 2, bfrE);
    stageB(o + 2, 1);
    BAR(); MFMAQ(3, bfrO); VMC(4); BAR();   // forces A(e+2), B(e+2)
  }

  // ---- epilogue: dout = acc + (Cb+Db), nontemporal ----
#pragma unroll
  for (int fj = 0; fj < 4; ++fj) {
    const int col = n0 + wn * 64 + fj * 16 + lr;
    const float cb = cbdb[col];
#pragma unroll
    for (int m = 0; m < 8; ++m) {
      const int rowb = m0 + wm * 128 + m * 16 + lk * 4;
#pragma unroll
      for (int j = 0; j < 4; ++j)
        __builtin_nontemporal_store(acc[m][fj][j] + cb,
                                    &dout[(size_t)(rowb + j) * DIM + col]);
    }
  }
#undef MFMAQ
#undef BAR
}

extern "C" void kernel_launch(void* const* d_in, const int* in_sizes, int n_in,
                              void* d_out, int out_size, void* d_ws, size_t ws_size,
                              hipStream_t stream) {
  const float* x  = (const float*)d_in[0];
  const float* A  = (const float*)d_in[1];
  const float* Bw = (const float*)d_in[2];
  const float* Bb = (const float*)d_in[3];
  const float* Cw = (const float*)d_in[4];
  const float* Cb = (const float*)d_in[5];
  const float* Dw = (const float*)d_in[6];
  const float* Db = (const float*)d_in[7];
  float* dout = (float*)d_out;

  char* ws = (char*)d_ws;
  unsigned short* xb   = (unsigned short*)(ws);              // 33,554,432 B
  unsigned short* bwb  = (unsigned short*)(ws + 33554432);   //    524,288 B
  unsigned short* wob  = (unsigned short*)(ws + 34078720);   //  2,621,440 B
  float*          G    = (float*)         (ws + 36700160);   // 16,777,216 B
  unsigned short* stb  = (unsigned short*)(ws + 53477376);   //  8,388,608 B
  float*          bb2  = (float*)         (ws + 61865984);   //      1,024 B
  float*          mP2  = (float*)         (ws + 61867008);   //      1,024 B
  float*          cbdb = (float*)         (ws + 61868032);   //      4,096 B -> 61,872,128

  // 1) weight conversion + constants (tiny)
  convert_w<<<256 + 1024 + 1, 256, 0, stream>>>(
      A, Bw, Bb, Cw, Cb, Dw, Db, bwb, wob, bb2, mP2, cbdb);
  // 2) fused: G = (x @ Bw^T)*C2 + bb2 ; xb = bf16(x)
  gemm_GX<<<512, 256, 0, stream>>>(x, bwb, G, bb2, xb);
  // 3) chunked recurrent scan -> states (bf16)
  scan_kernel<<<BATCH * 64, 256, 0, stream>>>(G, mP2, stb);
  // 4) dout = [states|x] @ [Cw|Dw]^T + (Cb+Db)
  gemm_out<<<256, 512, 0, stream>>>(stb, xb, wob, cbdb, dout);
}

// Round 10
// 91.014 us; speedup vs baseline: 1.1151x; 1.1151x over previous
//
#include <hip/hip_runtime.h>
#include <hip/hip_bf16.h>

#define DIM 1024
#define STATE 256
#define BATCH 4
#define SEQ 4096
#define M_TOT (BATCH * SEQ)  // 16384

typedef short short8 __attribute__((ext_vector_type(8)));
typedef float f32x4 __attribute__((ext_vector_type(4)));

__device__ __forceinline__ unsigned short f2bf(float f) {
  unsigned int u = __float_as_uint(f);
  u += 0x7fff + ((u >> 16) & 1);  // RNE
  return (unsigned short)(u >> 16);
}

__device__ __forceinline__ float bf2f(unsigned short u) {
  return __uint_as_float((unsigned int)u << 16);
}

__device__ __forceinline__ void gl_lds16(const void* g, void* l) {
  __builtin_amdgcn_global_load_lds(
      (const __attribute__((address_space(1))) void*)g,
      (__attribute__((address_space(3))) void*)l, 16, 0, 0);
}

#define C2F 2.8853900817779268f   // 2*log2(e)
#define LOG2EF 1.4426950408889634f
#define VMC(N) asm volatile("s_waitcnt vmcnt(" #N ")" ::: "memory")

// ---------------- convert_w: weights + constants only ------------------------
__global__ __launch_bounds__(256) void convert_w(
    const float* __restrict__ A, const float* __restrict__ Bw,
    const float* __restrict__ Bb, const float* __restrict__ Cw,
    const float* __restrict__ Cb, const float* __restrict__ Dw,
    const float* __restrict__ Db, unsigned short* __restrict__ bwb,
    unsigned short* __restrict__ wob, float* __restrict__ bb2,
    float* __restrict__ mP2, float* __restrict__ cbdb) {
  const int bx = blockIdx.x;
  const int t = threadIdx.x;
  if (bx < 256) {                      // bwb row per block
    int c = t * 4;
    const float4 v = *(const float4*)(Bw + (size_t)bx * DIM + c);
    *(ushort4*)(bwb + (size_t)bx * DIM + c) =
        make_ushort4(f2bf(v.x), f2bf(v.y), f2bf(v.z), f2bf(v.w));
  } else if (bx < 256 + 1024) {        // wob row e = [Cw[e,:] | Dw[e,:]]
    int e = bx - 256;
    if (t < 64) {
      const float4 v = *(const float4*)(Cw + (size_t)e * STATE + t * 4);
      *(ushort4*)(wob + (size_t)e * 1280 + t * 4) =
          make_ushort4(f2bf(v.x), f2bf(v.y), f2bf(v.z), f2bf(v.w));
    }
    const float4 v = *(const float4*)(Dw + (size_t)e * DIM + t * 4);
    *(ushort4*)(wob + (size_t)e * 1280 + 256 + t * 4) =
        make_ushort4(f2bf(v.x), f2bf(v.y), f2bf(v.z), f2bf(v.w));
  } else {                             // scan constants + out bias, one block
    const float P = C2F * __builtin_amdgcn_exp2f(A[t] * LOG2EF);
    bb2[t] = fmaf(Bb[t], C2F, P);
    mP2[t] = -2.0f * P;
#pragma unroll
    for (int k = 0; k < 4; ++k) {
      const int i = t * 4 + k;
      cbdb[i] = Cb[i] + Db[i];
    }
  }
}

// ---------------- gemm_GX v4: BK=64, 16 epochs, 2-slot ring, 2 blocks/CU -----
// G(bf16) = f2bf((x @ Bw^T)*C2 + bb2) ; xb = bf16(x) (wave t&3 stores tile t).
// BM=32, BN=256 (x read once; bwb L2-resident), BK=64, grid 512 = 2 blocks/CU.
// 2 slots x 40KB (A f32 8KB + B bf16 32KB). Distance-1 prefetch, full VMC(0)
// drain per epoch -- 16 epochs (was 32); co-resident block hides the drain.
// stage(t+2) is issued AFTER the barrier (slot t&1 just fully consumed: every
// wave's ds_reads were forced by MFMA use before its VMC+barrier). Layouts:
// A rows 256B XOR(r&7) on 16 chunks, B rows 128B XOR(r&7) (r4-proven): both
// resolve to <=2-way bank aliasing on reads.
__global__ __launch_bounds__(256, 2) void gemm_GX(
    const float* __restrict__ x,             // [16384][1024] f32
    const unsigned short* __restrict__ bwb,  // [256][1024] bf16
    unsigned short* __restrict__ G,          // [16384][256] bf16 (out)
    const float* __restrict__ bb2,
    unsigned short* __restrict__ xb)         // [16384][1024] bf16 (out)
{
  __shared__ char lds[81920];  // 2 slots x 40960 (A 8KB @0, B 32KB @8192)

  const int tid = threadIdx.x;
  const int wave = tid >> 6;   // n-column group 0..3
  const int lane = tid & 63;
  const int lr = lane & 15;
  const int lk = lane >> 4;
  const int m0 = blockIdx.x * 32;

  f32x4 acc[2][4];
#pragma unroll
  for (int i = 0; i < 2; ++i)
#pragma unroll
    for (int j = 0; j < 4; ++j) acc[i][j] = (f32x4){0.f, 0.f, 0.f, 0.f};

  const char* xB  = (const char*)x;
  const char* bwB = (const char*)bwb;
  char* xbB = (char*)xb;

  // stage K-tile kt (64 cols): A 2 loads/thr, B 8 loads/thr.
  auto stage = [&](int kt) {
    if (kt >= 16) return;
    char* slot = lds + (kt & 1) * 40960;
#pragma unroll
    for (int i = 0; i < 2; ++i) {   // A: [32 rows][256B f32], 16 chunks, XOR(r&7)
      const int s = i * 256 + tid;                // 512 slots of 16B
      const int r = s >> 4;
      const int c = (s & 15) ^ (r & 7);           // inverse-swizzled source
      gl_lds16(xB + (size_t)(m0 + r) * 4096 + (size_t)kt * 256 + c * 16,
               slot + i * 4096 + wave * 1024);
    }
#pragma unroll
    for (int i = 0; i < 8; ++i) {   // B: [256 rows][128B bf16], 8 chunks, XOR(r&7)
      const int s = i * 256 + tid;                // 2048 slots of 16B
      const int r = s >> 3;
      const int c = (s & 7) ^ (r & 7);
      gl_lds16(bwB + (size_t)r * 2048 + (size_t)kt * 128 + c * 16,
               slot + 8192 + i * 4096 + wave * 1024);
    }
  };

  // prologue
  stage(0);
  VMC(0);
  __builtin_amdgcn_s_barrier();
  stage(1);

  for (int t = 0; t < 16; ++t) {
    const char* As = lds + (t & 1) * 40960;
    const char* Bs = As + 8192;

    short8 af[2][2];  // [kk][f]
#pragma unroll
    for (int kk = 0; kk < 2; ++kk)
#pragma unroll
      for (int f = 0; f < 2; ++f) {
        const int row = f * 16 + lr;
        const int sw = row & 7;
        const f32x4 a0 = *(const f32x4*)(As + row * 256 + (((kk * 8 + 2 * lk)     ^ sw) << 4));
        const f32x4 a1 = *(const f32x4*)(As + row * 256 + (((kk * 8 + 2 * lk + 1) ^ sw) << 4));
        short8 v;
#pragma unroll
        for (int j = 0; j < 4; ++j) {
          v[j]     = (short)f2bf(a0[j]);
          v[4 + j] = (short)f2bf(a1[j]);
        }
        af[kk][f] = v;
      }
    short8 bfr[2][4];
#pragma unroll
    for (int kk = 0; kk < 2; ++kk)
#pragma unroll
      for (int fj = 0; fj < 4; ++fj) {
        const int n = wave * 64 + fj * 16 + lr;
        bfr[kk][fj] = *(const short8*)(Bs + n * 128 + (((kk * 4 + lk) ^ (n & 7)) << 4));
      }
#pragma unroll
    for (int kk = 0; kk < 2; ++kk)
#pragma unroll
      for (int f = 0; f < 2; ++f)
#pragma unroll
        for (int fj = 0; fj < 4; ++fj)
          acc[f][fj] = __builtin_amdgcn_mfma_f32_16x16x32_bf16(
              af[kk][f], bfr[kk][fj], acc[f][fj], 0, 0, 0);

    // xb write: wave w owns tiles t%4==w (4 short8 stores, full 32x64 tile)
    if ((t & 3) == wave) {
#pragma unroll
      for (int kk = 0; kk < 2; ++kk)
#pragma unroll
        for (int f = 0; f < 2; ++f) {
          const int row = f * 16 + lr;
          *(short8*)(xbB + (size_t)(m0 + row) * 2048 +
                     (size_t)t * 128 + kk * 64 + lk * 16) = af[kk][f];
        }
    }

    if (t < 15) {
      VMC(0);                       // drain st(t+1) (+ any stores)
      __builtin_amdgcn_s_barrier(); // all waves' reads of slot t&1 consumed
      stage(t + 2);                 // refill slot t&1
    }
  }

  // epilogue: G = bf16(acc*C2 + bb2)
#pragma unroll
  for (int f = 0; f < 2; ++f)
#pragma unroll
    for (int fj = 0; fj < 4; ++fj)
#pragma unroll
      for (int j = 0; j < 4; ++j) {
        const int rg = m0 + f * 16 + lk * 4 + j;
        const int cg = wave * 64 + fj * 16 + lr;
        G[(size_t)rg * STATE + cg] = f2bf(fmaf(acc[f][fj][j], C2F, bb2[cg]));
      }
}

// ---------------- chunked-parallel scan with warmup (G now bf16) --------------
// W=128: contraction |exp(A)(1-s^2)| ~0.85-0.95/step -> warmup error <~1.4e-3.
__global__ __launch_bounds__(256) void scan_kernel(
    const unsigned short* __restrict__ G, const float* __restrict__ mP2arr,
    unsigned short* __restrict__ states) {
  const int b = blockIdx.x >> 6;
  const int chunk = blockIdx.x & 63;
  const int n = threadIdx.x;
  const int t0 = chunk * 64;
  const int start = (t0 > 128) ? (t0 - 128) : 0;
  const int nw = t0 - start;
  const int total = nw + 64;

  const unsigned short* g = G + ((size_t)b * SEQ + start) * STATE + n;
  unsigned short* q = states + ((size_t)b * SEQ + start) * STATE + n;
  const float mP2 = mP2arr[n];

  float r = 0.5f;
  constexpr int CH = 16;
  float cur[CH], nxt[CH];
#pragma unroll
  for (int j = 0; j < CH; ++j) cur[j] = bf2f(g[(size_t)j * STATE]);

  const int NC = total / CH;
  for (int c = 0; c < NC; ++c) {
    if (c + 1 < NC) {
      const unsigned short* pn = g + (size_t)(c + 1) * CH * STATE;
#pragma unroll
      for (int j = 0; j < CH; ++j) nxt[j] = bf2f(pn[(size_t)j * STATE]);
    }
    if (c * CH >= nw) {
      unsigned short* qc = q + (size_t)c * CH * STATE;
#pragma unroll
      for (int j = 0; j < CH; ++j) {
        const float t = fmaf(mP2, r, cur[j]);
        const float e = __builtin_amdgcn_exp2f(t);
        r = __builtin_amdgcn_rcpf(1.0f + e);
        const float s = fmaf(-2.0f, r, 1.0f);
        qc[(size_t)j * STATE] = f2bf(s);
      }
    } else {
#pragma unroll
      for (int j = 0; j < CH; ++j) {
        const float t = fmaf(mP2, r, cur[j]);
        const float e = __builtin_amdgcn_exp2f(t);
        r = __builtin_amdgcn_rcpf(1.0f + e);
      }
    }
    if (c + 1 < NC) {
#pragma unroll
      for (int j = 0; j < CH; ++j) cur[j] = nxt[j];
    }
  }
}

// ---------------- gemm_out: dout = [states|x] @ [Cw|Dw]^T + (Cb+Db) ----------
// EXACT round-6 kernel (best measured 49.4us; r9's variant regressed, reverted).
#define PH(TILE, Q, STG, VMST)                                                 \
  do {                                                                         \
    const char* As = lds + ((TILE) & 1) * 32768;                               \
    const char* Bs = lds + 65536 + ((TILE) & 1) * 32768;                       \
    if ((Q) == 0) {                                                            \
      _Pragma("unroll") for (int fj = 0; fj < 4; ++fj) {                       \
        const int r = wn * 64 + fj * 16 + lr;                                  \
        _Pragma("unroll") for (int kk = 0; kk < 2; ++kk)                       \
          bfr[fj][kk] = *(const short8*)(Bs + r * 128 +                        \
                                         (((kk * 4 + lk) ^ (r & 7)) << 4));    \
      }                                                                        \
    }                                                                          \
    short8 af[2][2];                                                           \
    _Pragma("unroll") for (int fl = 0; fl < 2; ++fl) {                         \
      const int r = wm * 128 + (Q) * 32 + fl * 16 + lr;                        \
      _Pragma("unroll") for (int kk = 0; kk < 2; ++kk)                         \
        af[fl][kk] = *(const short8*)(As + r * 128 +                           \
                                      (((kk * 4 + lk) ^ (r & 7)) << 4));       \
    }                                                                          \
    STG;                                                                       \
    if ((Q) == 0) asm volatile("s_waitcnt lgkmcnt(8)" ::: "memory");           \
    __builtin_amdgcn_s_barrier();                                              \
    __builtin_amdgcn_s_setprio(1);                                             \
    _Pragma("unroll") for (int kk = 0; kk < 2; ++kk)                           \
      _Pragma("unroll") for (int fl = 0; fl < 2; ++fl)                         \
        _Pragma("unroll") for (int fj = 0; fj < 4; ++fj)                       \
          acc[(Q) * 2 + fl][fj] = __builtin_amdgcn_mfma_f32_16x16x32_bf16(     \
              af[fl][kk], bfr[fj][kk], acc[(Q) * 2 + fl][fj], 0, 0, 0);        \
    __builtin_amdgcn_s_setprio(0);                                             \
    VMST;                                                                      \
    __builtin_amdgcn_s_barrier();                                              \
  } while (0)

__global__ __launch_bounds__(512, 2) void gemm_out(
    const unsigned short* __restrict__ stb,  // [16384][256] bf16
    const unsigned short* __restrict__ xb,   // [16384][1024] bf16
    const unsigned short* __restrict__ wob,  // [1024][1280] bf16
    const float* __restrict__ cbdb,          // [1024]
    float* __restrict__ dout)                // [16384][1024] f32
{
  __shared__ char lds[131072];  // A: 2x32KB @0, B: 2x32KB @65536

  const int tid = threadIdx.x;
  const int wave = tid >> 6;
  const int lane = tid & 63;
  const int lr = lane & 15;
  const int lk = lane >> 4;
  const int wm = wave >> 2;  // 0..1
  const int wn = wave & 3;   // 0..3

  const int bs = ((blockIdx.x & 7) << 5) | (blockIdx.x >> 3);  // XCD swizzle
  const int m0 = (bs >> 2) * 256;
  const int n0 = (bs & 3) * 256;

  const char* stbB = (const char*)stb;
  const char* xbB  = (const char*)xb;
  const char* wobB = (const char*)wob;

  f32x4 acc[8][4];
#pragma unroll
  for (int i = 0; i < 8; ++i)
#pragma unroll
    for (int j = 0; j < 4; ++j) acc[i][j] = (f32x4){0.f, 0.f, 0.f, 0.f};

  auto stageA = [&](int kt, int h) {
    if (kt >= 20) return;
    const char* base;
    size_t str;
    size_t colb;
    if (kt < 4) { base = stbB; str = 512;  colb = (size_t)kt * 128; }
    else        { base = xbB;  str = 2048; colb = (size_t)(kt - 4) * 128; }
    base += (size_t)m0 * str;
#pragma unroll
    for (int i2 = 0; i2 < 2; ++i2) {
      const int s = i2 * 512 + tid;
      const int r = s >> 3;
      const int cl = (s & 7) ^ (r & 7);
      gl_lds16(base + (size_t)(h * 128 + r) * str + colb + cl * 16,
               lds + ((kt & 1) * 32768) + h * 16384 + i2 * 8192 + wave * 1024);
    }
  };
  auto stageB = [&](int kt, int h) {
    if (kt >= 20) return;
#pragma unroll
    for (int i2 = 0; i2 < 2; ++i2) {
      const int s = i2 * 512 + tid;
      const int r = s >> 3;
      const int cl = (s & 7) ^ (r & 7);
      gl_lds16(wobB + (size_t)(n0 + h * 128 + r) * 2560 + (size_t)kt * 128 + cl * 16,
               lds + 65536 + ((kt & 1) * 32768) + h * 16384 + i2 * 8192 + wave * 1024);
    }
  };

  // ---- prologue: A(0), B(0), B(1) = 6 half-tiles (12 loads/wave) ----
  stageA(0, 0); stageA(0, 1);
  stageB(0, 0); stageB(0, 1);
  stageB(1, 0); stageB(1, 1);
  VMC(4);  // A(0),B(0) complete; B(1)'s 4 loads may fly
  __builtin_amdgcn_s_barrier();

  short8 bfr[4][2];
  for (int i = 0; i < 10; ++i) {
    const int e = 2 * i, o = e + 1;
    PH(e, 0, stageA(o, 0), );
    PH(e, 1, stageA(o, 1), );
    PH(e, 2, stageB(e + 2, 0), );
    PH(e, 3, stageB(e + 2, 1), if (i == 9) { VMC(0); } else { VMC(4); });
    PH(o, 0, stageA(e + 2, 0), );
    PH(o, 1, stageA(e + 2, 1), );
    PH(o, 2, stageB(o + 2, 0), );
    PH(o, 3, stageB(o + 2, 1), VMC(4));
  }

  // ---- epilogue: dout = acc + (Cb+Db) ----
#pragma unroll
  for (int fj = 0; fj < 4; ++fj) {
    const int col = n0 + wn * 64 + fj * 16 + lr;
    const float cb = cbdb[col];
#pragma unroll
    for (int m = 0; m < 8; ++m) {
      const int rowb = m0 + wm * 128 + m * 16 + lk * 4;
#pragma unroll
      for (int j = 0; j < 4; ++j)
        dout[(size_t)(rowb + j) * DIM + col] = acc[m][fj][j] + cb;
    }
  }
}

extern "C" void kernel_launch(void* const* d_in, const int* in_sizes, int n_in,
                              void* d_out, int out_size, void* d_ws, size_t ws_size,
                              hipStream_t stream) {
  const float* x  = (const float*)d_in[0];
  const float* A  = (const float*)d_in[1];
  const float* Bw = (const float*)d_in[2];
  const float* Bb = (const float*)d_in[3];
  const float* Cw = (const float*)d_in[4];
  const float* Cb = (const float*)d_in[5];
  const float* Dw = (const float*)d_in[6];
  const float* Db = (const float*)d_in[7];
  float* dout = (float*)d_out;

  char* ws = (char*)d_ws;
  unsigned short* xb   = (unsigned short*)(ws);              // 33,554,432 B
  unsigned short* bwb  = (unsigned short*)(ws + 33554432);   //    524,288 B
  unsigned short* wob  = (unsigned short*)(ws + 34078720);   //  2,621,440 B
  unsigned short* G    = (unsigned short*)(ws + 36700160);   //  8,388,608 B (bf16 now)
  unsigned short* stb  = (unsigned short*)(ws + 53477376);   //  8,388,608 B
  float*          bb2  = (float*)         (ws + 61865984);   //      1,024 B
  float*          mP2  = (float*)         (ws + 61867008);   //      1,024 B
  float*          cbdb = (float*)         (ws + 61868032);   //      4,096 B -> 61,872,128

  // 1) weight conversion + constants (tiny)
  convert_w<<<256 + 1024 + 1, 256, 0, stream>>>(
      A, Bw, Bb, Cw, Cb, Dw, Db, bwb, wob, bb2, mP2, cbdb);
  // 2) fused: G(bf16) = (x @ Bw^T)*C2 + bb2 ; xb = bf16(x)  [v4: 16 epochs]
  gemm_GX<<<512, 256, 0, stream>>>(x, bwb, G, bb2, xb);
  // 3) chunked recurrent scan -> states (bf16)
  scan_kernel<<<BATCH * 64, 256, 0, stream>>>(G, mP2, stb);
  // 4) dout = [states|x] @ [Cw|Dw]^T + (Cb+Db)
  gemm_out<<<256, 512, 0, stream>>>(stb, xb, wob, cbdb, dout);
}